// Round 9
// baseline (361.036 us; speedup 1.0000x reference)
//
#include <hip/hip_runtime.h>
#include <math.h>

#define SEQL 197
#define HD 768
#define NH 12
#define DHD 64
#define BATCH 64
#define OUTD 1000

typedef unsigned short ushort_t;
typedef __attribute__((ext_vector_type(8))) short bf16x8;
typedef __attribute__((ext_vector_type(4))) float f32x4;

static __device__ __forceinline__ unsigned short f2bf(float f) {
    union { float f; unsigned u; } v; v.f = f;
    unsigned r = v.u + 0x7fff + ((v.u >> 16) & 1);
    return (unsigned short)(r >> 16);
}

static __device__ __forceinline__ void gload16(const ushort_t* g, ushort_t* l) {
    __builtin_amdgcn_global_load_lds(
        (const __attribute__((address_space(1))) unsigned int*)g,
        (__attribute__((address_space(3))) unsigned int*)l, 16, 0, 0);
}

// ---------------- positional embedding table ----------------
__global__ void k_pos(float* __restrict__ pos) {
    int i = blockIdx.x * 256 + threadIdx.x;
    if (i >= SEQL * HD) return;
    int s = i / HD, d = i % HD;
    float f = (float)(d & ~1);
    float r = powf(10000.0f, -f / (float)HD);
    float a = (float)s * r;
    pos[i] = (d & 1) ? cosf(a) : sinf(a);
}

// ---------------- cls row of tokens ----------------
__global__ void k_cls(const float* __restrict__ cls_tok, const float* __restrict__ pos,
                      float* __restrict__ tok) {
    int i = blockIdx.x * 256 + threadIdx.x;
    if (i >= BATCH * HD) return;
    int b = i / HD, e = i % HD;
    tok[(b * SEQL) * HD + e] = cls_tok[e] + pos[e];
}

// ---------------- W (f32 [K][N]) -> W^T bf16 [N][K], K=N=768 ----------------
__global__ void k_cvtW(const float* __restrict__ W, ushort_t* __restrict__ WT) {
    int idx = blockIdx.x * 256 + threadIdx.x;       // 0 .. 768*192
    if (idx >= 768 * 192) return;
    int k = idx / 192, nq = idx % 192;
    float4 w = *(const float4*)&W[k * 768 + nq * 4];
    WT[(nq * 4 + 0) * 768 + k] = f2bf(w.x);
    WT[(nq * 4 + 1) * 768 + k] = f2bf(w.y);
    WT[(nq * 4 + 2) * 768 + k] = f2bf(w.z);
    WT[(nq * 4 + 3) * 768 + k] = f2bf(w.w);
}

// ---------------- Wq/Wk/Wv [12][64 d][64 e] f32 -> wt bf16 [3][12][64 e][64 d] ----
__global__ void k_cvtWqkv(const float* __restrict__ Wq, const float* __restrict__ Wk,
                          const float* __restrict__ Wv, ushort_t* __restrict__ wt) {
    int idx = blockIdx.x * 256 + threadIdx.x;       // over 3*12*64*16 = 36864
    if (idx >= 36864) return;
    int dq = idx & 15;
    int e  = (idx >> 4) & 63;
    int h  = (idx >> 10) % 12;
    int pj = idx / 12288;
    const float* W = (pj == 0) ? Wq : (pj == 1) ? Wk : Wv;
    ushort4 o;
    o.x = f2bf(W[(h * 64 + dq * 4 + 0) * 64 + e]);
    o.y = f2bf(W[(h * 64 + dq * 4 + 1) * 64 + e]);
    o.z = f2bf(W[(h * 64 + dq * 4 + 2) * 64 + e]);
    o.w = f2bf(W[(h * 64 + dq * 4 + 3) * 64 + e]);
    *(ushort4*)&wt[(size_t)((pj * 12 + h) * 64 + e) * 64 + dq * 4] = o;
}

// ---------------- gather patches -> bf16 A [12544][768] ----------------
__global__ void k_prep_patches(const float* __restrict__ img, ushort_t* __restrict__ Ae) {
    int idx = blockIdx.x * 256 + threadIdx.x;       // 0 .. 12544*192
    int m = idx / 192, kq = idx % 192;
    int k0 = kq * 4;
    int c = k0 >> 8, rem = k0 & 255, ir = rem >> 4, jc = rem & 15;
    int b = m / 196, pi = m % 196;
    int pr = pi / 14, pc = pi % 14;
    float4 v = *(const float4*)&img[((b * 3 + c) * 224 + pr * 16 + ir) * 224 + pc * 16 + jc];
    ushort4 o;
    o.x = f2bf(v.x); o.y = f2bf(v.y); o.z = f2bf(v.z); o.w = f2bf(v.w);
    *(ushort4*)&Ae[m * 768 + k0] = o;
}

// ---------------- bf16 MFMA GEMM, 128x128 tile, BK=64, 4 waves ----------------
template <int MODE>
__launch_bounds__(256)
__global__ void k_gemm_bf16(const ushort_t* __restrict__ A, const ushort_t* __restrict__ Bt,
                            const float* __restrict__ bias, const float* __restrict__ pos,
                            float* __restrict__ out, int Mtot) {
    __shared__ ushort_t As[128 * 64];
    __shared__ ushort_t Bs[128 * 64];
    const int m0 = blockIdx.x * 128;
    const int n0 = blockIdx.y * 128;
    const int tid = threadIdx.x;
    const int lane = tid & 63, wave = tid >> 6;
    const int wm = wave >> 1, wn = wave & 1;

    f32x4 acc[4][4];
#pragma unroll
    for (int i = 0; i < 4; ++i)
#pragma unroll
        for (int j = 0; j < 4; ++j)
#pragma unroll
            for (int r = 0; r < 4; ++r) acc[i][j][r] = 0.f;

    for (int kt = 0; kt < 12; ++kt) {
        const int k0 = kt * 64;
#pragma unroll
        for (int t = 0; t < 4; ++t) {
            int c = (wave << 2) | t;
            int o = c * 1024 + lane * 16;
            int row = o >> 7;
            int inner = o & 127;
            int col = (inner ^ ((row & 7) << 4)) >> 1;
            gload16(&A[(size_t)(m0 + row) * 768 + k0 + col], &As[c * 512]);
            gload16(&Bt[(size_t)(n0 + row) * 768 + k0 + col], &Bs[c * 512]);
        }
        __syncthreads();
#pragma unroll
        for (int ks = 0; ks < 2; ++ks) {
            const int cbyte = ks * 64 + (lane >> 4) * 16;
            bf16x8 af[4], bf[4];
#pragma unroll
            for (int mi = 0; mi < 4; ++mi) {
                int row = wm * 64 + mi * 16 + (lane & 15);
                af[mi] = *(const bf16x8*)((const char*)As + row * 128 + (cbyte ^ ((row & 7) << 4)));
            }
#pragma unroll
            for (int ni = 0; ni < 4; ++ni) {
                int n = wn * 64 + ni * 16 + (lane & 15);
                bf[ni] = *(const bf16x8*)((const char*)Bs + n * 128 + (cbyte ^ ((n & 7) << 4)));
            }
#pragma unroll
            for (int mi = 0; mi < 4; ++mi)
#pragma unroll
                for (int ni = 0; ni < 4; ++ni)
                    acc[mi][ni] = __builtin_amdgcn_mfma_f32_16x16x32_bf16(af[mi], bf[ni], acc[mi][ni], 0, 0, 0);
        }
        __syncthreads();
    }

    const int colb = n0 + wn * 64 + (lane & 15);
    const int rowb = m0 + wm * 64 + (lane >> 4) * 4;
#pragma unroll
    for (int ni = 0; ni < 4; ++ni) {
        const int n = colb + ni * 16;
        const float bn = bias[n];
#pragma unroll
        for (int mi = 0; mi < 4; ++mi) {
#pragma unroll
            for (int r = 0; r < 4; ++r) {
                int m = rowb + mi * 16 + r;
                if (MODE == 0) {
                    int b = m / 196, s = 1 + m % 196;
                    out[((b * SEQL) + s) * HD + n] = acc[mi][ni][r] + bn + pos[s * HD + n];
                } else {
                    if (m < Mtot) {
                        float* p = &out[(size_t)m * HD + n];
                        *p = *p + fmaxf(acc[mi][ni][r] + bn, 0.f);
                    }
                }
            }
        }
    }
}

// ---------------- 2D LayerNorm stats (mean, rsigma) per image ----------------
__global__ void k_lnstats(const float* __restrict__ buf, float* __restrict__ stats, int which) {
    int b = blockIdx.x;
    const float* p = buf + (size_t)b * SEQL * HD;
    float s = 0.f, s2 = 0.f;
    const int NV = SEQL * HD / 4;
    for (int i = threadIdx.x; i < NV; i += 256) {
        float4 v = ((const float4*)p)[i];
        s += v.x + v.y + v.z + v.w;
        s2 += v.x * v.x + v.y * v.y + v.z * v.z + v.w * v.w;
    }
    __shared__ float rs[8], rs2[8];
#pragma unroll
    for (int off = 32; off > 0; off >>= 1) {
        s += __shfl_down(s, off);
        s2 += __shfl_down(s2, off);
    }
    int lane = threadIdx.x & 63, w = threadIdx.x >> 6;
    if (lane == 0) { rs[w] = s; rs2[w] = s2; }
    __syncthreads();
    if (threadIdx.x == 0) {
        float S = 0.f, S2 = 0.f;
        for (int i = 0; i < 4; ++i) { S += rs[i]; S2 += rs2[i]; }
        const float inv_n = 1.0f / (float)(SEQL * HD);
        float mu = S * inv_n;
        float var = S2 * inv_n - mu * mu;
        stats[which * 128 + b * 2] = mu;
        stats[which * 128 + b * 2 + 1] = rsqrtf(var + 1e-5f);
    }
}

// ---------------- FUSED v2: LN1 + QKV + full-softmax attention + residual ----
// Grid (12 h, 64 b, 2 half). 4 waves / 256 threads. Each block: FULL K/V for
// the head (redundant across the 2 halves - MFMA is cheap) + 128 q-rows.
// LDS 80,896 B -> 2 blocks/CU (vs 1 before): independent blocks overlap phases.
// Swapped QK^T (S^T = K @ Q^T) so P/V stores pack as b64.
__launch_bounds__(256, 2)
__global__ void k_qkvattn(const float* __restrict__ tok, const float* __restrict__ stats,
                          const float* __restrict__ g1, const float* __restrict__ b1,
                          const ushort_t* __restrict__ wt,
                          const float* __restrict__ bq, const float* __restrict__ bk,
                          const float* __restrict__ bv, float* __restrict__ out) {
    const int h = blockIdx.x, b = blockIdx.y, half = blockIdx.z;
    __shared__ __attribute__((aligned(16))) ushort_t Ksm[256 * 72];   // [t][d] (stride 72)
    __shared__ __attribute__((aligned(16))) ushort_t Vsm[64 * 264];   // [e][t] (stride 264)
    __shared__ __attribute__((aligned(16))) ushort_t Psm[4 * 32 * 40];// per-wave [32 q][40] Qtmp/P
    const int tid = threadIdx.x;
    const int wave = tid >> 6, lane = tid & 63;
    const int l16 = lane & 15, l4 = lane >> 4;
    const float mu = stats[b * 2], rsg = stats[b * 2 + 1];
    ushort_t* myP = &Psm[wave * 1280];

    // LN1(X) fragment loader: row s (global seq idx), 8 cols at d0 of head slice
#define LDX(dst, s, d0)                                                                  \
    {                                                                                    \
        if ((s) < SEQL) {                                                                \
            const float* tp = &tok[((size_t)b * SEQL + (s)) * HD + h * 64 + (d0)];       \
            const float* gp = &g1[(size_t)(s) * HD + h * 64 + (d0)];                     \
            const float* bp = &b1[(size_t)(s) * HD + h * 64 + (d0)];                     \
            float4 t0 = *(const float4*)&tp[0], t1 = *(const float4*)&tp[4];             \
            float4 ga = *(const float4*)&gp[0], gb = *(const float4*)&gp[4];             \
            float4 ba = *(const float4*)&bp[0], bb = *(const float4*)&bp[4];             \
            dst[0] = (short)f2bf((t0.x - mu) * rsg * ga.x + ba.x);                       \
            dst[1] = (short)f2bf((t0.y - mu) * rsg * ga.y + ba.y);                       \
            dst[2] = (short)f2bf((t0.z - mu) * rsg * ga.z + ba.z);                       \
            dst[3] = (short)f2bf((t0.w - mu) * rsg * ga.w + ba.w);                       \
            dst[4] = (short)f2bf((t1.x - mu) * rsg * gb.x + bb.x);                       \
            dst[5] = (short)f2bf((t1.y - mu) * rsg * gb.y + bb.y);                       \
            dst[6] = (short)f2bf((t1.z - mu) * rsg * gb.z + bb.z);                       \
            dst[7] = (short)f2bf((t1.w - mu) * rsg * gb.w + bb.w);                       \
        } else {                                                                         \
            _Pragma("unroll") for (int _j = 0; _j < 8; ++_j) dst[_j] = 0;                \
        }                                                                                \
    }

    // ---- Phase 1: K,V projections for t-rows [wave*64, wave*64+64) ----
    {
        bf16x8 wK[4][2], wV[4][2];
        float bk4[4], bv4[4];
#pragma unroll
        for (int ni = 0; ni < 4; ++ni) {
            const size_t wrK = (size_t)((1 * 12 + h) * 64 + ni * 16 + l16) * 64;
            const size_t wrV = (size_t)((2 * 12 + h) * 64 + ni * 16 + l16) * 64;
            wK[ni][0] = *(const bf16x8*)&wt[wrK + l4 * 8];
            wK[ni][1] = *(const bf16x8*)&wt[wrK + 32 + l4 * 8];
            wV[ni][0] = *(const bf16x8*)&wt[wrV + l4 * 8];
            wV[ni][1] = *(const bf16x8*)&wt[wrV + 32 + l4 * 8];
            bk4[ni] = bk[h * 64 + ni * 16 + l16];
            bv4[ni] = bv[h * 64 + ni * 16 + l16];
        }
        const int Tb = wave * 64;
#pragma unroll
        for (int mi = 0; mi < 4; ++mi) {
            const int trow = Tb + mi * 16 + l16;
            bf16x8 a0, a1;
            LDX(a0, trow, l4 * 8);
            LDX(a1, trow, 32 + l4 * 8);
            f32x4 ka[4], va[4];
#pragma unroll
            for (int ni = 0; ni < 4; ++ni) {
                ka[ni][0] = 0.f; ka[ni][1] = 0.f; ka[ni][2] = 0.f; ka[ni][3] = 0.f;
                va[ni][0] = 0.f; va[ni][1] = 0.f; va[ni][2] = 0.f; va[ni][3] = 0.f;
            }
#pragma unroll
            for (int ni = 0; ni < 4; ++ni) {
                ka[ni] = __builtin_amdgcn_mfma_f32_16x16x32_bf16(a0, wK[ni][0], ka[ni], 0, 0, 0);
                ka[ni] = __builtin_amdgcn_mfma_f32_16x16x32_bf16(a1, wK[ni][1], ka[ni], 0, 0, 0);
                va[ni] = __builtin_amdgcn_mfma_f32_16x16x32_bf16(a0, wV[ni][0], va[ni], 0, 0, 0);
                va[ni] = __builtin_amdgcn_mfma_f32_16x16x32_bf16(a1, wV[ni][1], va[ni], 0, 0, 0);
            }
            const int t4 = Tb + mi * 16 + l4 * 4;
#pragma unroll
            for (int ni = 0; ni < 4; ++ni) {
#pragma unroll
                for (int r = 0; r < 4; ++r)
                    Ksm[(t4 + r) * 72 + ni * 16 + l16] = f2bf(ka[ni][r] + bk4[ni]);
                ushort4 pk;
                pk.x = f2bf(va[ni][0] + bv4[ni]);
                pk.y = f2bf(va[ni][1] + bv4[ni]);
                pk.z = f2bf(va[ni][2] + bv4[ni]);
                pk.w = f2bf(va[ni][3] + bv4[ni]);
                *(ushort4*)&Vsm[(ni * 16 + l16) * 264 + t4] = pk;
            }
        }
    }

    // ---- Phase 2: Q projection for q-rows [half*128 + wave*32, +32) ----
    bf16x8 qb[2][2];
    {
        bf16x8 wQ[4][2];
        float bq4[4];
#pragma unroll
        for (int ni = 0; ni < 4; ++ni) {
            const size_t wr = (size_t)((0 * 12 + h) * 64 + ni * 16 + l16) * 64;
            wQ[ni][0] = *(const bf16x8*)&wt[wr + l4 * 8];
            wQ[ni][1] = *(const bf16x8*)&wt[wr + 32 + l4 * 8];
            bq4[ni] = bq[h * 64 + ni * 16 + l16];
        }
        const int Qb = half * 128 + wave * 32;
        bf16x8 aq0[2], aq1[2];
#pragma unroll
        for (int mi = 0; mi < 2; ++mi) {
            LDX(aq0[mi], Qb + mi * 16 + l16, l4 * 8);
            LDX(aq1[mi], Qb + mi * 16 + l16, 32 + l4 * 8);
        }
        f32x4 qa_[2][4];
#pragma unroll
        for (int mi = 0; mi < 2; ++mi)
#pragma unroll
            for (int ni = 0; ni < 4; ++ni) {
                qa_[mi][ni][0] = 0.f; qa_[mi][ni][1] = 0.f;
                qa_[mi][ni][2] = 0.f; qa_[mi][ni][3] = 0.f;
                qa_[mi][ni] = __builtin_amdgcn_mfma_f32_16x16x32_bf16(aq0[mi], wQ[ni][0], qa_[mi][ni], 0, 0, 0);
                qa_[mi][ni] = __builtin_amdgcn_mfma_f32_16x16x32_bf16(aq1[mi], wQ[ni][1], qa_[mi][ni], 0, 0, 0);
            }
        // bounce through own P slice in two d-halves (32 cols each)
#pragma unroll
        for (int hf = 0; hf < 2; ++hf) {
#pragma unroll
            for (int nj = 0; nj < 2; ++nj) {
                int ni = hf * 2 + nj;
#pragma unroll
                for (int mi = 0; mi < 2; ++mi)
#pragma unroll
                    for (int r = 0; r < 4; ++r) {
                        int ql = mi * 16 + l4 * 4 + r;
                        myP[ql * 40 + nj * 16 + l16] = f2bf(qa_[mi][ni][r] + bq4[ni]);
                    }
            }
            qb[0][hf] = *(const bf16x8*)&myP[(l16) * 40 + l4 * 8];
            qb[1][hf] = *(const bf16x8*)&myP[(16 + l16) * 40 + l4 * 8];
        }
    }

    __syncthreads();   // K and V^T from all waves now visible

    // ---- Phase 3: swapped QK^T -> sa[ti][qi] holds S^T (rows t, cols q) ----
    f32x4 sa[16][2];
    __builtin_amdgcn_s_setprio(1);
#pragma unroll
    for (int ti = 0; ti < 16; ++ti) {
        const int t = ti * 16 + l16;
        bf16x8 k0 = *(const bf16x8*)&Ksm[t * 72 + l4 * 8];
        bf16x8 k1 = *(const bf16x8*)&Ksm[t * 72 + 32 + l4 * 8];
#pragma unroll
        for (int qi = 0; qi < 2; ++qi) {
            f32x4 z;
            z[0] = 0.f; z[1] = 0.f; z[2] = 0.f; z[3] = 0.f;
            z = __builtin_amdgcn_mfma_f32_16x16x32_bf16(k0, qb[qi][0], z, 0, 0, 0);
            sa[ti][qi] = __builtin_amdgcn_mfma_f32_16x16x32_bf16(k1, qb[qi][1], z, 0, 0, 0);
        }
    }
    __builtin_amdgcn_s_setprio(0);

    // ---- Phase 4: full softmax per q (q = qi*16+l16; t spans ti,r in-lane + l4) ----
    float invl[2];
#pragma unroll
    for (int qi = 0; qi < 2; ++qi) {
        float mt = -INFINITY;
#pragma unroll
        for (int ti = 0; ti < 16; ++ti)
#pragma unroll
            for (int r = 0; r < 4; ++r) {
                int t = ti * 16 + l4 * 4 + r;
                float s = sa[ti][qi][r] * 0.125f;
                if (t >= SEQL) s = -1e30f;
                sa[ti][qi][r] = s;
                mt = fmaxf(mt, s);
            }
        mt = fmaxf(mt, __shfl_xor(mt, 16));
        mt = fmaxf(mt, __shfl_xor(mt, 32));
        float rs = 0.f;
#pragma unroll
        for (int ti = 0; ti < 16; ++ti)
#pragma unroll
            for (int r = 0; r < 4; ++r) {
                float p = __expf(sa[ti][qi][r] - mt);
                sa[ti][qi][r] = p;
                rs += p;
            }
        rs += __shfl_xor(rs, 16);
        rs += __shfl_xor(rs, 32);
        invl[qi] = 1.0f / rs;
    }

    // ---- Phase 5: PV in 8 chunks of 32 t (P pre-normalized, b64-packed) ----
    f32x4 oacc[2][4];
#pragma unroll
    for (int mi = 0; mi < 2; ++mi)
#pragma unroll
        for (int ne = 0; ne < 4; ++ne) {
            oacc[mi][ne][0] = 0.f; oacc[mi][ne][1] = 0.f;
            oacc[mi][ne][2] = 0.f; oacc[mi][ne][3] = 0.f;
        }

#pragma unroll
    for (int c = 0; c < 8; ++c) {
#pragma unroll
        for (int qi = 0; qi < 2; ++qi) {
            const float il = invl[qi];
#pragma unroll
            for (int tj = 0; tj < 2; ++tj) {
                f32x4 pv = sa[c * 2 + tj][qi];
                ushort4 pk;
                pk.x = f2bf(pv[0] * il);
                pk.y = f2bf(pv[1] * il);
                pk.z = f2bf(pv[2] * il);
                pk.w = f2bf(pv[3] * il);
                *(ushort4*)&myP[(qi * 16 + l16) * 40 + tj * 16 + l4 * 4] = pk;
            }
        }
        bf16x8 pa0 = *(const bf16x8*)&myP[(l16) * 40 + l4 * 8];
        bf16x8 pa1 = *(const bf16x8*)&myP[(16 + l16) * 40 + l4 * 8];
        __builtin_amdgcn_s_setprio(1);
#pragma unroll
        for (int ne = 0; ne < 4; ++ne) {
            bf16x8 vv = *(const bf16x8*)&Vsm[(ne * 16 + l16) * 264 + c * 32 + l4 * 8];
            oacc[0][ne] = __builtin_amdgcn_mfma_f32_16x16x32_bf16(pa0, vv, oacc[0][ne], 0, 0, 0);
            oacc[1][ne] = __builtin_amdgcn_mfma_f32_16x16x32_bf16(pa1, vv, oacc[1][ne], 0, 0, 0);
        }
        __builtin_amdgcn_s_setprio(0);
    }

    // ---- epilogue: O + residual (P was pre-normalized) ----
    const int Qb = half * 128 + wave * 32;
#pragma unroll
    for (int mi = 0; mi < 2; ++mi)
#pragma unroll
        for (int r = 0; r < 4; ++r) {
            int row = Qb + mi * 16 + l4 * 4 + r;
            if (row < SEQL) {
                size_t off = ((size_t)b * SEQL + row) * HD + h * 64;
#pragma unroll
                for (int ne = 0; ne < 4; ++ne) {
                    int e = ne * 16 + l16;
                    out[off + e] = oacc[mi][ne][r] + tok[off + e];
                }
            }
        }
#undef LDX
}

// ---------------- LN2 apply -> bf16 A for encoder GEMM ----------------
__global__ void k_ln2apply(const float* __restrict__ outb, const float* __restrict__ stats,
                           const float* __restrict__ g2, const float* __restrict__ b2,
                           ushort_t* __restrict__ x) {
    int i = blockIdx.x * 256 + threadIdx.x;
    if (i >= BATCH * SEQL * HD / 4) return;
    int e4 = i * 4;
    int m = e4 / HD, kk = e4 % HD;
    int b = m / SEQL, s = m % SEQL;
    float mu = stats[128 + b * 2], rsg = stats[128 + b * 2 + 1];
    float4 t = *(const float4*)&outb[e4];
    float4 g = *(const float4*)&g2[s * HD + kk];
    float4 bb = *(const float4*)&b2[s * HD + kk];
    ushort4 o;
    o.x = f2bf((t.x - mu) * rsg * g.x + bb.x);
    o.y = f2bf((t.y - mu) * rsg * g.y + bb.y);
    o.z = f2bf((t.z - mu) * rsg * g.z + bb.z);
    o.w = f2bf((t.w - mu) * rsg * g.w + bb.w);
    *(ushort4*)&x[e4] = o;
}

// ---------------- classifier head + softmax ----------------
__launch_bounds__(256)
__global__ void k_head(const float* __restrict__ out, const float* __restrict__ Wo,
                       const float* __restrict__ bo, float* __restrict__ dout) {
    const int b = blockIdx.x, tid = threadIdx.x;
    __shared__ float cls[768];
    __shared__ float red[256];
    for (int i = tid; i < 192; i += 256)
        *(float4*)&cls[i * 4] = *(const float4*)&out[(b * SEQL) * HD + i * 4];
    __syncthreads();

    const int o0 = tid * 4;
    const bool ok = (o0 < OUTD);
    float4 acc = {0.f, 0.f, 0.f, 0.f};
    if (ok) {
        acc = *(const float4*)&bo[o0];
        for (int e = 0; e < 768; ++e) {
            float c = cls[e];
            float4 w = *(const float4*)&Wo[e * OUTD + o0];
            acc.x += c * w.x;
            acc.y += c * w.y;
            acc.z += c * w.z;
            acc.w += c * w.w;
        }
    }
    float mx = ok ? fmaxf(fmaxf(acc.x, acc.y), fmaxf(acc.z, acc.w)) : -INFINITY;
    red[tid] = mx;
    __syncthreads();
    for (int s = 128; s > 0; s >>= 1) {
        if (tid < s) red[tid] = fmaxf(red[tid], red[tid + s]);
        __syncthreads();
    }
    float M = red[0];
    __syncthreads();
    float4 p = {0.f, 0.f, 0.f, 0.f};
    float ls = 0.f;
    if (ok) {
        p.x = expf(acc.x - M);
        p.y = expf(acc.y - M);
        p.z = expf(acc.z - M);
        p.w = expf(acc.w - M);
        ls = p.x + p.y + p.z + p.w;
    }
    red[tid] = ls;
    __syncthreads();
    for (int s = 128; s > 0; s >>= 1) {
        if (tid < s) red[tid] += red[tid + s];
        __syncthreads();
    }
    float inv = 1.0f / red[0];
    if (ok) {
        p.x *= inv; p.y *= inv; p.z *= inv; p.w *= inv;
        *(float4*)&dout[b * OUTD + o0] = p;
    }
}

extern "C" void kernel_launch(void* const* d_in, const int* in_sizes, int n_in,
                              void* d_out, int out_size, void* d_ws, size_t ws_size,
                              hipStream_t stream) {
    const float* images  = (const float*)d_in[0];
    const float* W_map   = (const float*)d_in[1];
    const float* b_map   = (const float*)d_in[2];
    const float* cls_tok = (const float*)d_in[3];
    const float* ln1_g   = (const float*)d_in[4];
    const float* ln1_b   = (const float*)d_in[5];
    const float* Wq      = (const float*)d_in[6];
    const float* bq      = (const float*)d_in[7];
    const float* Wk      = (const float*)d_in[8];
    const float* bk      = (const float*)d_in[9];
    const float* Wv      = (const float*)d_in[10];
    const float* bv      = (const float*)d_in[11];
    const float* ln2_g   = (const float*)d_in[12];
    const float* ln2_b   = (const float*)d_in[13];
    const float* W_enc   = (const float*)d_in[14];
    const float* b_enc   = (const float*)d_in[15];
    const float* W_out   = (const float*)d_in[16];
    const float* b_out   = (const float*)d_in[17];

    float* ws = (float*)d_ws;
    const size_t BIG = (size_t)BATCH * SEQL * HD;     // 9,682,944

    float* pos   = ws;
    float* tok   = ws + 151552;
    float* outb  = tok + BIG;
    float* stats = outb + BIG;                        // 256 f32
    ushort_t* wtq = (ushort_t*)(stats + 256);         // bf16 [3][12][64][64] = 36864
    // Ae sized 12672 rows: holds 12544-row patch matrix AND the 12608-row LN2
    // output, plus enc GEMM tail-tile reads stay in-bounds (masked, finite).
    ushort_t* Ae  = wtq + 36864;                      // bf16 [12672][768]
    ushort_t* WmT = Ae + (size_t)12672 * 768;         // bf16 [768][768]
    // overlays (dead regions reused):
    ushort_t* Ae2 = Ae;                               // LN2-out bf16 (Ae dead after embed GEMM)
    ushort_t* WeT = WmT;                              // W_enc^T bf16 (WmT dead after embed GEMM)

    k_pos<<<591, 256, 0, stream>>>(pos);
    k_cls<<<192, 256, 0, stream>>>(cls_tok, pos, tok);
    k_cvtW<<<576, 256, 0, stream>>>(W_map, WmT);
    k_prep_patches<<<9408, 256, 0, stream>>>(images, Ae);
    k_gemm_bf16<0><<<dim3(98, 6), 256, 0, stream>>>(Ae, WmT, b_map, pos, tok, 12544);
    k_lnstats<<<64, 256, 0, stream>>>(tok, stats, 0);
    k_cvtWqkv<<<144, 256, 0, stream>>>(Wq, Wk, Wv, wtq);
    k_qkvattn<<<dim3(12, 64, 2), 256, 0, stream>>>(tok, stats, ln1_g, ln1_b, wtq, bq, bk, bv, outb);
    k_cvtW<<<576, 256, 0, stream>>>(W_enc, WeT);
    k_lnstats<<<64, 256, 0, stream>>>(outb, stats, 1);
    k_ln2apply<<<9456, 256, 0, stream>>>(outb, stats, ln2_g, ln2_b, Ae2);
    k_gemm_bf16<1><<<dim3(99, 6), 256, 0, stream>>>(Ae2, WeT, b_enc, pos, outb, 12608);
    k_head<<<64, 256, 0, stream>>>(outb, W_out, b_out, (float*)d_out);
}

// Round 11
// 300.366 us; speedup vs baseline: 1.2020x; 1.2020x over previous
//
#include <hip/hip_runtime.h>
#include <math.h>

#define SEQL 197
#define HD 768
#define NH 12
#define DHD 64
#define BATCH 64
#define OUTD 1000

typedef unsigned short ushort_t;
typedef __attribute__((ext_vector_type(8))) short bf16x8;
typedef __attribute__((ext_vector_type(4))) float f32x4;

static __device__ __forceinline__ unsigned short f2bf(float f) {
    union { float f; unsigned u; } v; v.f = f;
    unsigned r = v.u + 0x7fff + ((v.u >> 16) & 1);
    return (unsigned short)(r >> 16);
}

static __device__ __forceinline__ void gload16(const ushort_t* g, ushort_t* l) {
    __builtin_amdgcn_global_load_lds(
        (const __attribute__((address_space(1))) unsigned int*)g,
        (__attribute__((address_space(3))) unsigned int*)l, 16, 0, 0);
}

// ---------------- init: positional table + cls row of tokens ----------------
// pos[s=0] is analytically [0,1,0,1,...] so cls needs no dependency on pos.
__global__ void k_init(const float* __restrict__ cls_tok, float* __restrict__ pos,
                       float* __restrict__ tok) {
    int i = blockIdx.x * 256 + threadIdx.x;
    if (i < SEQL * HD) {
        int s = i / HD, d = i % HD;
        float f = (float)(d & ~1);
        float r = powf(10000.0f, -f / (float)HD);
        float a = (float)s * r;
        pos[i] = (d & 1) ? cosf(a) : sinf(a);
    } else {
        int j = i - SEQL * HD;
        if (j < BATCH * HD) {
            int b = j / HD, e = j % HD;
            tok[(b * SEQL) * HD + e] = cls_tok[e] + ((e & 1) ? 1.0f : 0.0f);
        }
    }
}

// ---------------- all weight conversions in one kernel ----------------
// W_map -> WmT [768n][768k], W_enc -> WeT [768n][768k], Wq/Wk/Wv -> wt [3][12][64e][64d]
__global__ void k_cvtAll(const float* __restrict__ W_map, const float* __restrict__ W_enc,
                         const float* __restrict__ Wq, const float* __restrict__ Wk,
                         const float* __restrict__ Wv,
                         ushort_t* __restrict__ WmT, ushort_t* __restrict__ WeT,
                         ushort_t* __restrict__ wt) {
    int idx = blockIdx.x * 256 + threadIdx.x;
    if (idx < 2 * 147456) {
        const float* W = (idx < 147456) ? W_map : W_enc;
        ushort_t* WT   = (idx < 147456) ? WmT : WeT;
        int i = (idx < 147456) ? idx : idx - 147456;
        int k = i / 192, nq = i % 192;
        float4 w = *(const float4*)&W[k * 768 + nq * 4];
        WT[(nq * 4 + 0) * 768 + k] = f2bf(w.x);
        WT[(nq * 4 + 1) * 768 + k] = f2bf(w.y);
        WT[(nq * 4 + 2) * 768 + k] = f2bf(w.z);
        WT[(nq * 4 + 3) * 768 + k] = f2bf(w.w);
    } else {
        int i = idx - 2 * 147456;
        if (i < 36864) {
            int dq = i & 15;
            int e  = (i >> 4) & 63;
            int h  = (i >> 10) % 12;
            int pj = i / 12288;
            const float* W = (pj == 0) ? Wq : (pj == 1) ? Wk : Wv;
            ushort4 o;
            o.x = f2bf(W[(h * 64 + dq * 4 + 0) * 64 + e]);
            o.y = f2bf(W[(h * 64 + dq * 4 + 1) * 64 + e]);
            o.z = f2bf(W[(h * 64 + dq * 4 + 2) * 64 + e]);
            o.w = f2bf(W[(h * 64 + dq * 4 + 3) * 64 + e]);
            *(ushort4*)&wt[(size_t)((pj * 12 + h) * 64 + e) * 64 + dq * 4] = o;
        }
    }
}

// ---------------- gather patches -> bf16 A [12544][768] ----------------
__global__ void k_prep_patches(const float* __restrict__ img, ushort_t* __restrict__ Ae) {
    int idx = blockIdx.x * 256 + threadIdx.x;       // 0 .. 12544*192
    int m = idx / 192, kq = idx % 192;
    int k0 = kq * 4;
    int c = k0 >> 8, rem = k0 & 255, ir = rem >> 4, jc = rem & 15;
    int b = m / 196, pi = m % 196;
    int pr = pi / 14, pc = pi % 14;
    float4 v = *(const float4*)&img[((b * 3 + c) * 224 + pr * 16 + ir) * 224 + pc * 16 + jc];
    ushort4 o;
    o.x = f2bf(v.x); o.y = f2bf(v.y); o.z = f2bf(v.z); o.w = f2bf(v.w);
    *(ushort4*)&Ae[m * 768 + k0] = o;
}

// ---------------- bf16 MFMA GEMM, 128x128 tile, BK=64, 4 waves ----------------
template <int MODE>
__launch_bounds__(256)
__global__ void k_gemm_bf16(const ushort_t* __restrict__ A, const ushort_t* __restrict__ Bt,
                            const float* __restrict__ bias, const float* __restrict__ pos,
                            float* __restrict__ out, int Mtot) {
    __shared__ ushort_t As[128 * 64];
    __shared__ ushort_t Bs[128 * 64];
    const int m0 = blockIdx.x * 128;
    const int n0 = blockIdx.y * 128;
    const int tid = threadIdx.x;
    const int lane = tid & 63, wave = tid >> 6;
    const int wm = wave >> 1, wn = wave & 1;

    f32x4 acc[4][4];
#pragma unroll
    for (int i = 0; i < 4; ++i)
#pragma unroll
        for (int j = 0; j < 4; ++j)
#pragma unroll
            for (int r = 0; r < 4; ++r) acc[i][j][r] = 0.f;

    for (int kt = 0; kt < 12; ++kt) {
        const int k0 = kt * 64;
#pragma unroll
        for (int t = 0; t < 4; ++t) {
            int c = (wave << 2) | t;
            int o = c * 1024 + lane * 16;
            int row = o >> 7;
            int inner = o & 127;
            int col = (inner ^ ((row & 7) << 4)) >> 1;
            gload16(&A[(size_t)(m0 + row) * 768 + k0 + col], &As[c * 512]);
            gload16(&Bt[(size_t)(n0 + row) * 768 + k0 + col], &Bs[c * 512]);
        }
        __syncthreads();
#pragma unroll
        for (int ks = 0; ks < 2; ++ks) {
            const int cbyte = ks * 64 + (lane >> 4) * 16;
            bf16x8 af[4], bf[4];
#pragma unroll
            for (int mi = 0; mi < 4; ++mi) {
                int row = wm * 64 + mi * 16 + (lane & 15);
                af[mi] = *(const bf16x8*)((const char*)As + row * 128 + (cbyte ^ ((row & 7) << 4)));
            }
#pragma unroll
            for (int ni = 0; ni < 4; ++ni) {
                int n = wn * 64 + ni * 16 + (lane & 15);
                bf[ni] = *(const bf16x8*)((const char*)Bs + n * 128 + (cbyte ^ ((n & 7) << 4)));
            }
#pragma unroll
            for (int mi = 0; mi < 4; ++mi)
#pragma unroll
                for (int ni = 0; ni < 4; ++ni)
                    acc[mi][ni] = __builtin_amdgcn_mfma_f32_16x16x32_bf16(af[mi], bf[ni], acc[mi][ni], 0, 0, 0);
        }
        __syncthreads();
    }

    const int colb = n0 + wn * 64 + (lane & 15);
    const int rowb = m0 + wm * 64 + (lane >> 4) * 4;
#pragma unroll
    for (int ni = 0; ni < 4; ++ni) {
        const int n = colb + ni * 16;
        const float bn = bias[n];
#pragma unroll
        for (int mi = 0; mi < 4; ++mi) {
#pragma unroll
            for (int r = 0; r < 4; ++r) {
                int m = rowb + mi * 16 + r;
                if (MODE == 0) {
                    int b = m / 196, s = 1 + m % 196;
                    out[((b * SEQL) + s) * HD + n] = acc[mi][ni][r] + bn + pos[s * HD + n];
                } else {
                    if (m < Mtot) {
                        float* p = &out[(size_t)m * HD + n];
                        *p = *p + fmaxf(acc[mi][ni][r] + bn, 0.f);
                    }
                }
            }
        }
    }
}

// ---------------- LN1 stats (mean, rsigma) per image; also zeroes LN2 raw sums ----
__global__ void k_lnstats(const float* __restrict__ buf, float* __restrict__ stats) {
    int b = blockIdx.x;
    if (b == 0 && threadIdx.x < 128) stats[128 + threadIdx.x] = 0.f;   // zero LN2 accum
    const float* p = buf + (size_t)b * SEQL * HD;
    float s = 0.f, s2 = 0.f;
    const int NV = SEQL * HD / 4;
    for (int i = threadIdx.x; i < NV; i += 256) {
        float4 v = ((const float4*)p)[i];
        s += v.x + v.y + v.z + v.w;
        s2 += v.x * v.x + v.y * v.y + v.z * v.z + v.w * v.w;
    }
    __shared__ float rs[8], rs2[8];
#pragma unroll
    for (int off = 32; off > 0; off >>= 1) {
        s += __shfl_down(s, off);
        s2 += __shfl_down(s2, off);
    }
    int lane = threadIdx.x & 63, w = threadIdx.x >> 6;
    if (lane == 0) { rs[w] = s; rs2[w] = s2; }
    __syncthreads();
    if (threadIdx.x == 0) {
        float S = 0.f, S2 = 0.f;
        for (int i = 0; i < 4; ++i) { S += rs[i]; S2 += rs2[i]; }
        const float inv_n = 1.0f / (float)(SEQL * HD);
        float mu = S * inv_n;
        float var = S2 * inv_n - mu * mu;
        stats[b * 2] = mu;
        stats[b * 2 + 1] = rsqrtf(var + 1e-5f);
    }
}

// ---------------- FUSED: LN1 + QKV projections + flash attention + residual ----
// (round-8 structure, 1 block/(h,b), 8 waves) + setprio on MFMA clusters +
// LN2 raw-sum accumulation fused into the epilogue.
__launch_bounds__(512, 2)
__global__ void k_qkvattn(const float* __restrict__ tok, float* __restrict__ stats,
                          const float* __restrict__ g1, const float* __restrict__ b1,
                          const ushort_t* __restrict__ wt,
                          const float* __restrict__ bq, const float* __restrict__ bk,
                          const float* __restrict__ bv, float* __restrict__ out) {
    const int h = blockIdx.x, b = blockIdx.y;
    __shared__ __attribute__((aligned(16))) ushort_t sm[51712];
    __shared__ float rS[8], rS2[8];
    const int tid = threadIdx.x;
    const int wave = tid >> 6, lane = tid & 63;
    const int l16 = lane & 15, l4 = lane >> 4;
    const int r0 = wave * 32;
    const float mu = stats[b * 2], rsg = stats[b * 2 + 1];

    // ---- stage LN1(X) rows (each wave stages exactly its own 32 rows) ----
    {
        const int row = tid >> 1, hw = tid & 1;
        if (row < SEQL) {
            const float* tp = &tok[((size_t)b * SEQL + row) * HD + h * 64 + hw * 32];
            const float* gp = &g1[(size_t)row * HD + h * 64 + hw * 32];
            const float* bp = &b1[(size_t)row * HD + h * 64 + hw * 32];
#pragma unroll
            for (int g = 0; g < 4; ++g) {
                float4 t0 = *(const float4*)&tp[g * 8];
                float4 t1 = *(const float4*)&tp[g * 8 + 4];
                float4 ga = *(const float4*)&gp[g * 8];
                float4 gb = *(const float4*)&gp[g * 8 + 4];
                float4 ba = *(const float4*)&bp[g * 8];
                float4 bb = *(const float4*)&bp[g * 8 + 4];
                bf16x8 o;
                o[0] = (short)f2bf((t0.x - mu) * rsg * ga.x + ba.x);
                o[1] = (short)f2bf((t0.y - mu) * rsg * ga.y + ba.y);
                o[2] = (short)f2bf((t0.z - mu) * rsg * ga.z + ba.z);
                o[3] = (short)f2bf((t0.w - mu) * rsg * ga.w + ba.w);
                o[4] = (short)f2bf((t1.x - mu) * rsg * gb.x + bb.x);
                o[5] = (short)f2bf((t1.y - mu) * rsg * gb.y + bb.y);
                o[6] = (short)f2bf((t1.z - mu) * rsg * gb.z + bb.z);
                o[7] = (short)f2bf((t1.w - mu) * rsg * gb.w + bb.w);
                int pc = (hw * 32 + g * 8) ^ ((row & 7) << 3);
                *(bf16x8*)&sm[row * 64 + pc] = o;
            }
        } else {
            bf16x8 z;
#pragma unroll
            for (int j = 0; j < 8; ++j) z[j] = 0;
#pragma unroll
            for (int g = 0; g < 4; ++g) {
                int pc = (hw * 32 + g * 8) ^ ((row & 7) << 3);
                *(bf16x8*)&sm[row * 64 + pc] = z;
            }
        }
    }

    // A fragments from own rows (wave-private slice; no barrier needed)
    bf16x8 af[2][2];
#pragma unroll
    for (int mi = 0; mi < 2; ++mi)
#pragma unroll
        for (int kk = 0; kk < 2; ++kk) {
            int row = r0 + mi * 16 + l16;
            af[mi][kk] = *(const bf16x8*)&sm[row * 64 + ((kk * 32 + l4 * 8) ^ ((row & 7) << 3))];
        }

    ushort_t* myS = &sm[wave * 2048];   // wave-private 32x64 slice (Qtmp, then P)

#define PROJ_ACC(PJ, ACC)                                                                      \
    {                                                                                          \
        _Pragma("unroll") for (int ni = 0; ni < 4; ++ni) {                                     \
            const ushort_t* wr = &wt[(size_t)(((PJ) * 12 + h) * 64 + ni * 16 + l16) * 64];     \
            bf16x8 w0 = *(const bf16x8*)&wr[l4 * 8];                                           \
            bf16x8 w1 = *(const bf16x8*)&wr[32 + l4 * 8];                                      \
            _Pragma("unroll") for (int mi = 0; mi < 2; ++mi) {                                 \
                ACC[mi][ni] = __builtin_amdgcn_mfma_f32_16x16x32_bf16(af[mi][0], w0, ACC[mi][ni], 0, 0, 0); \
                ACC[mi][ni] = __builtin_amdgcn_mfma_f32_16x16x32_bf16(af[mi][1], w1, ACC[mi][ni], 0, 0, 0); \
            }                                                                                  \
        }                                                                                      \
    }

    f32x4 acc[2][4];
#define ZERO_ACC                                                                               \
    _Pragma("unroll") for (int mi = 0; mi < 2; ++mi)                                           \
        _Pragma("unroll") for (int ni = 0; ni < 4; ++ni) {                                     \
            acc[mi][ni][0] = 0.f; acc[mi][ni][1] = 0.f; acc[mi][ni][2] = 0.f; acc[mi][ni][3] = 0.f; }

    // ---- Q ----
    ZERO_ACC;
    PROJ_ACC(0, acc);
#pragma unroll
    for (int ni = 0; ni < 4; ++ni) {
        float bn = bq[h * 64 + ni * 16 + l16];
#pragma unroll
        for (int mi = 0; mi < 2; ++mi)
#pragma unroll
            for (int r = 0; r < 4; ++r) {
                int rl = mi * 16 + l4 * 4 + r;
                myS[rl * 64 + ((ni * 16 + l16) ^ ((rl & 7) << 3))] = f2bf(acc[mi][ni][r] + bn);
            }
    }
    bf16x8 qa[2][2];
#pragma unroll
    for (int mi = 0; mi < 2; ++mi)
#pragma unroll
        for (int kk = 0; kk < 2; ++kk) {
            int rl = mi * 16 + l16;
            qa[mi][kk] = *(const bf16x8*)&myS[rl * 64 + ((kk * 32 + l4 * 8) ^ ((rl & 7) << 3))];
        }

    // ---- K ----
    ZERO_ACC;
    PROJ_ACC(1, acc);
#pragma unroll
    for (int ni = 0; ni < 4; ++ni) {
        float bn = bk[h * 64 + ni * 16 + l16];
#pragma unroll
        for (int mi = 0; mi < 2; ++mi)
#pragma unroll
            for (int r = 0; r < 4; ++r) {
                int t = r0 + mi * 16 + l4 * 4 + r;
                sm[16384 + t * 72 + ni * 16 + l16] = f2bf(acc[mi][ni][r] + bn);
            }
    }

    // ---- V (transposed store) ----
    ZERO_ACC;
    PROJ_ACC(2, acc);
#pragma unroll
    for (int ni = 0; ni < 4; ++ni) {
        float bn = bv[h * 64 + ni * 16 + l16];
#pragma unroll
        for (int mi = 0; mi < 2; ++mi)
#pragma unroll
            for (int r = 0; r < 4; ++r) {
                int t = r0 + mi * 16 + l4 * 4 + r;
                sm[34816 + (ni * 16 + l16) * 264 + t] = f2bf(acc[mi][ni][r] + bn);
            }
    }

    __syncthreads();   // K and V^T now visible to all waves

    // ---- QK^T over all 256 t ----
    f32x4 sa[2][16];
    __builtin_amdgcn_s_setprio(1);
#pragma unroll
    for (int ni = 0; ni < 16; ++ni) {
        int t = ni * 16 + l16;
        bf16x8 k0 = *(const bf16x8*)&sm[16384 + t * 72 + l4 * 8];
        bf16x8 k1 = *(const bf16x8*)&sm[16384 + t * 72 + 32 + l4 * 8];
#pragma unroll
        for (int mi = 0; mi < 2; ++mi) {
            f32x4 z;
            z[0] = 0.f; z[1] = 0.f; z[2] = 0.f; z[3] = 0.f;
            z = __builtin_amdgcn_mfma_f32_16x16x32_bf16(qa[mi][0], k0, z, 0, 0, 0);
            sa[mi][ni] = __builtin_amdgcn_mfma_f32_16x16x32_bf16(qa[mi][1], k1, z, 0, 0, 0);
        }
    }
    __builtin_amdgcn_s_setprio(0);

    // ---- full softmax per q-row ----
    float l_s[2][4];
#pragma unroll
    for (int mi = 0; mi < 2; ++mi)
#pragma unroll
        for (int r = 0; r < 4; ++r) {
            float mt = -INFINITY;
#pragma unroll
            for (int ni = 0; ni < 16; ++ni) {
                float s = sa[mi][ni][r] * 0.125f;
                if (ni * 16 + l16 >= SEQL) s = -1e30f;
                sa[mi][ni][r] = s;
                mt = fmaxf(mt, s);
            }
            mt = fmaxf(mt, __shfl_xor(mt, 1));
            mt = fmaxf(mt, __shfl_xor(mt, 2));
            mt = fmaxf(mt, __shfl_xor(mt, 4));
            mt = fmaxf(mt, __shfl_xor(mt, 8));
            float rsum = 0.f;
#pragma unroll
            for (int ni = 0; ni < 16; ++ni) {
                float p = __expf(sa[mi][ni][r] - mt);
                sa[mi][ni][r] = p;
                rsum += p;
            }
            rsum += __shfl_xor(rsum, 1);
            rsum += __shfl_xor(rsum, 2);
            rsum += __shfl_xor(rsum, 4);
            rsum += __shfl_xor(rsum, 8);
            l_s[mi][r] = rsum;
        }

    // ---- PV in 4 chunks of 64 t (P bounced through wave-private slice) ----
    f32x4 oacc[2][4];
#pragma unroll
    for (int mi = 0; mi < 2; ++mi)
#pragma unroll
        for (int ne = 0; ne < 4; ++ne) {
            oacc[mi][ne][0] = 0.f; oacc[mi][ne][1] = 0.f;
            oacc[mi][ne][2] = 0.f; oacc[mi][ne][3] = 0.f;
        }

    for (int c = 0; c < 4; ++c) {
#pragma unroll
        for (int j = 0; j < 4; ++j)
#pragma unroll
            for (int mi = 0; mi < 2; ++mi)
#pragma unroll
                for (int r = 0; r < 4; ++r) {
                    int rl = mi * 16 + l4 * 4 + r;
                    myS[rl * 64 + ((j * 16 + l16) ^ ((rl & 7) << 3))] = f2bf(sa[mi][c * 4 + j][r]);
                }
        bf16x8 pa[2][2];
#pragma unroll
        for (int mi = 0; mi < 2; ++mi)
#pragma unroll
            for (int kk = 0; kk < 2; ++kk) {
                int rl = mi * 16 + l16;
                pa[mi][kk] = *(const bf16x8*)&myS[rl * 64 + ((kk * 32 + l4 * 8) ^ ((rl & 7) << 3))];
            }
        __builtin_amdgcn_s_setprio(1);
#pragma unroll
        for (int ne = 0; ne < 4; ++ne) {
            int e = ne * 16 + l16;
            bf16x8 v0 = *(const bf16x8*)&sm[34816 + e * 264 + c * 64 + l4 * 8];
            bf16x8 v1 = *(const bf16x8*)&sm[34816 + e * 264 + c * 64 + 32 + l4 * 8];
#pragma unroll
            for (int mi = 0; mi < 2; ++mi) {
                oacc[mi][ne] = __builtin_amdgcn_mfma_f32_16x16x32_bf16(pa[mi][0], v0, oacc[mi][ne], 0, 0, 0);
                oacc[mi][ne] = __builtin_amdgcn_mfma_f32_16x16x32_bf16(pa[mi][1], v1, oacc[mi][ne], 0, 0, 0);
            }
        }
        __builtin_amdgcn_s_setprio(0);
    }

    // ---- epilogue: O/l + residual, + LN2 raw-sum accumulation ----
    float psum = 0.f, psq = 0.f;
#pragma unroll
    for (int mi = 0; mi < 2; ++mi)
#pragma unroll
        for (int r = 0; r < 4; ++r) {
            int row = r0 + mi * 16 + l4 * 4 + r;
            if (row < SEQL) {
                float inv = 1.0f / l_s[mi][r];
                size_t off = ((size_t)b * SEQL + row) * HD + h * 64;
#pragma unroll
                for (int ne = 0; ne < 4; ++ne) {
                    int e = ne * 16 + l16;
                    float o = oacc[mi][ne][r] * inv + tok[off + e];
                    out[off + e] = o;
                    psum += o;
                    psq += o * o;
                }
            }
        }
#pragma unroll
    for (int off = 32; off > 0; off >>= 1) {
        psum += __shfl_down(psum, off);
        psq += __shfl_down(psq, off);
    }
    if (lane == 0) { rS[wave] = psum; rS2[wave] = psq; }
    __syncthreads();
    if (tid == 0) {
        float S = 0.f, S2 = 0.f;
#pragma unroll
        for (int i = 0; i < 8; ++i) { S += rS[i]; S2 += rS2[i]; }
        atomicAdd(&stats[128 + 2 * b], S);
        atomicAdd(&stats[129 + 2 * b], S2);
    }
#undef PROJ_ACC
#undef ZERO_ACC
}

// ---------------- LN2 apply (finalizes stats from raw sums) -> bf16 ----------------
__global__ void k_ln2apply(const float* __restrict__ outb, const float* __restrict__ stats,
                           const float* __restrict__ g2, const float* __restrict__ b2,
                           ushort_t* __restrict__ x) {
    int i = blockIdx.x * 256 + threadIdx.x;
    if (i >= BATCH * SEQL * HD / 4) return;
    int e4 = i * 4;
    int m = e4 / HD, kk = e4 % HD;
    int b = m / SEQL, s = m % SEQL;
    const float inv_n = 1.0f / (float)(SEQL * HD);
    float S = stats[128 + 2 * b], S2 = stats[129 + 2 * b];
    float mu = S * inv_n;
    float rsg = rsqrtf(S2 * inv_n - mu * mu + 1e-5f);
    float4 t = *(const float4*)&outb[e4];
    float4 g = *(const float4*)&g2[s * HD + kk];
    float4 bb = *(const float4*)&b2[s * HD + kk];
    ushort4 o;
    o.x = f2bf((t.x - mu) * rsg * g.x + bb.x);
    o.y = f2bf((t.y - mu) * rsg * g.y + bb.y);
    o.z = f2bf((t.z - mu) * rsg * g.z + bb.z);
    o.w = f2bf((t.w - mu) * rsg * g.w + bb.w);
    *(ushort4*)&x[e4] = o;
}

// ---------------- classifier head + softmax ----------------
__launch_bounds__(256)
__global__ void k_head(const float* __restrict__ out, const float* __restrict__ Wo,
                       const float* __restrict__ bo, float* __restrict__ dout) {
    const int b = blockIdx.x, tid = threadIdx.x;
    __shared__ float cls[768];
    __shared__ float red[256];
    for (int i = tid; i < 192; i += 256)
        *(float4*)&cls[i * 4] = *(const float4*)&out[(b * SEQL) * HD + i * 4];
    __syncthreads();

    const int o0 = tid * 4;
    const bool ok = (o0 < OUTD);
    float4 acc = {0.f, 0.f, 0.f, 0.f};
    if (ok) {
        acc = *(const float4*)&bo[o0];
        for (int e = 0; e < 768; ++e) {
            float c = cls[e];
            float4 w = *(const float4*)&Wo[e * OUTD + o0];
            acc.x += c * w.x;
            acc.y += c * w.y;
            acc.z += c * w.z;
            acc.w += c * w.w;
        }
    }
    float mx = ok ? fmaxf(fmaxf(acc.x, acc.y), fmaxf(acc.z, acc.w)) : -INFINITY;
    red[tid] = mx;
    __syncthreads();
    for (int s = 128; s > 0; s >>= 1) {
        if (tid < s) red[tid] = fmaxf(red[tid], red[tid + s]);
        __syncthreads();
    }
    float M = red[0];
    __syncthreads();
    float4 p = {0.f, 0.f, 0.f, 0.f};
    float ls = 0.f;
    if (ok) {
        p.x = expf(acc.x - M);
        p.y = expf(acc.y - M);
        p.z = expf(acc.z - M);
        p.w = expf(acc.w - M);
        ls = p.x + p.y + p.z + p.w;
    }
    red[tid] = ls;
    __syncthreads();
    for (int s = 128; s > 0; s >>= 1) {
        if (tid < s) red[tid] += red[tid + s];
        __syncthreads();
    }
    float inv = 1.0f / red[0];
    if (ok) {
        p.x *= inv; p.y *= inv; p.z *= inv; p.w *= inv;
        *(float4*)&dout[b * OUTD + o0] = p;
    }
}

extern "C" void kernel_launch(void* const* d_in, const int* in_sizes, int n_in,
                              void* d_out, int out_size, void* d_ws, size_t ws_size,
                              hipStream_t stream) {
    const float* images  = (const float*)d_in[0];
    const float* W_map   = (const float*)d_in[1];
    const float* b_map   = (const float*)d_in[2];
    const float* cls_tok = (const float*)d_in[3];
    const float* ln1_g   = (const float*)d_in[4];
    const float* ln1_b   = (const float*)d_in[5];
    const float* Wq      = (const float*)d_in[6];
    const float* bq      = (const float*)d_in[7];
    const float* Wk      = (const float*)d_in[8];
    const float* bk      = (const float*)d_in[9];
    const float* Wv      = (const float*)d_in[10];
    const float* bv      = (const float*)d_in[11];
    const float* ln2_g   = (const float*)d_in[12];
    const float* ln2_b   = (const float*)d_in[13];
    const float* W_enc   = (const float*)d_in[14];
    const float* b_enc   = (const float*)d_in[15];
    const float* W_out   = (const float*)d_in[16];
    const float* b_out   = (const float*)d_in[17];

    float* ws = (float*)d_ws;
    const size_t BIG = (size_t)BATCH * SEQL * HD;     // 9,682,944

    float* pos   = ws;
    float* tok   = ws + 151552;
    float* outb  = tok + BIG;
    float* stats = outb + BIG;                        // 256 f32 (LN1 final + LN2 raw sums)
    // wtq holds [3][12][64][64] = 147,456 bf16 elements (round-10 bug: was
    // sized 36,864, so Wq h>=9 / Wk / Wv physically lived inside Ae and got
    // clobbered once conversions moved before k_prep_patches).
    ushort_t* wtq = (ushort_t*)(stats + 256);         // bf16, 147456 elems
    ushort_t* Ae  = wtq + 147456;                     // bf16 [12672][768] (patches, then LN2 out)
    ushort_t* WmT = Ae + (size_t)12672 * 768;         // bf16 [768][768]
    ushort_t* WeT = WmT + (size_t)768 * 768;          // bf16 [768][768] (separate — no overlay)
    ushort_t* Ae2 = Ae;                               // LN2-out bf16 (Ae dead after embed GEMM)

    k_init<<<783, 256, 0, stream>>>(cls_tok, pos, tok);
    k_cvtAll<<<1296, 256, 0, stream>>>(W_map, W_enc, Wq, Wk, Wv, WmT, WeT, wtq);
    k_prep_patches<<<9408, 256, 0, stream>>>(images, Ae);
    k_gemm_bf16<0><<<dim3(98, 6), 256, 0, stream>>>(Ae, WmT, b_map, pos, tok, 12544);
    k_lnstats<<<64, 256, 0, stream>>>(tok, stats);
    k_qkvattn<<<dim3(12, 64), 512, 0, stream>>>(tok, stats, ln1_g, ln1_b, wtq, bq, bk, bv, outb);
    k_ln2apply<<<9456, 256, 0, stream>>>(outb, stats, ln2_g, ln2_b, Ae2);
    k_gemm_bf16<1><<<dim3(99, 6), 256, 0, stream>>>(Ae2, WeT, b_enc, pos, outb, 12608);
    k_head<<<64, 256, 0, stream>>>(outb, W_out, b_out, (float*)d_out);
}

// Round 12
// 261.736 us; speedup vs baseline: 1.3794x; 1.1476x over previous
//
#include <hip/hip_runtime.h>
#include <math.h>

#define SEQL 197
#define HD 768
#define NH 12
#define DHD 64
#define BATCH 64
#define OUTD 1000

typedef unsigned short ushort_t;
typedef __attribute__((ext_vector_type(8))) short bf16x8;
typedef __attribute__((ext_vector_type(4))) float f32x4;

static __device__ __forceinline__ unsigned short f2bf(float f) {
    union { float f; unsigned u; } v; v.f = f;
    unsigned r = v.u + 0x7fff + ((v.u >> 16) & 1);
    return (unsigned short)(r >> 16);
}

static __device__ __forceinline__ void gload16(const ushort_t* g, ushort_t* l) {
    __builtin_amdgcn_global_load_lds(
        (const __attribute__((address_space(1))) unsigned int*)g,
        (__attribute__((address_space(3))) unsigned int*)l, 16, 0, 0);
}

// ---------------- init: positional table + cls row of tokens (+LN1 cls sums) ----
// pos[s=0] is analytically [0,1,0,1,...]. Branch boundary 151296 is 64-aligned,
// so no wave straddles the two branches; cls waves are b-uniform (768%64==0).
__global__ void k_init(const float* __restrict__ cls_tok, float* __restrict__ pos,
                       float* __restrict__ tok, float* __restrict__ stats) {
    int i = blockIdx.x * 256 + threadIdx.x;
    if (i < SEQL * HD) {
        int s = i / HD, d = i % HD;
        float f = (float)(d & ~1);
        float r = powf(10000.0f, -f / (float)HD);
        float a = (float)s * r;
        pos[i] = (d & 1) ? cosf(a) : sinf(a);
    } else {
        int j = i - SEQL * HD;
        if (j < BATCH * HD) {
            int b = j / HD, e = j % HD;
            float v = cls_tok[e] + ((e & 1) ? 1.0f : 0.0f);
            tok[(b * SEQL) * HD + e] = v;
            float sv = v, qv = v * v;
#pragma unroll
            for (int off = 32; off > 0; off >>= 1) {
                sv += __shfl_down(sv, off);
                qv += __shfl_down(qv, off);
            }
            if ((threadIdx.x & 63) == 0) {
                atomicAdd(&stats[2 * b], sv);
                atomicAdd(&stats[2 * b + 1], qv);
            }
        }
    }
}

// ---------------- all weight conversions in one kernel (+ zero stats) ----------
__global__ void k_cvtAll(const float* __restrict__ W_map, const float* __restrict__ W_enc,
                         const float* __restrict__ Wq, const float* __restrict__ Wk,
                         const float* __restrict__ Wv,
                         ushort_t* __restrict__ WmT, ushort_t* __restrict__ WeT,
                         ushort_t* __restrict__ wt, float* __restrict__ stats) {
    int idx = blockIdx.x * 256 + threadIdx.x;
    if (blockIdx.x == 0 && threadIdx.x < 256) stats[threadIdx.x] = 0.f;  // runs first
    if (idx < 2 * 147456) {
        const float* W = (idx < 147456) ? W_map : W_enc;
        ushort_t* WT   = (idx < 147456) ? WmT : WeT;
        int i = (idx < 147456) ? idx : idx - 147456;
        int k = i / 192, nq = i % 192;
        float4 w = *(const float4*)&W[k * 768 + nq * 4];
        WT[(nq * 4 + 0) * 768 + k] = f2bf(w.x);
        WT[(nq * 4 + 1) * 768 + k] = f2bf(w.y);
        WT[(nq * 4 + 2) * 768 + k] = f2bf(w.z);
        WT[(nq * 4 + 3) * 768 + k] = f2bf(w.w);
    } else {
        int i = idx - 2 * 147456;
        if (i < 36864) {
            int dq = i & 15;
            int e  = (i >> 4) & 63;
            int h  = (i >> 10) % 12;
            int pj = i / 12288;
            const float* W = (pj == 0) ? Wq : (pj == 1) ? Wk : Wv;
            ushort4 o;
            o.x = f2bf(W[(h * 64 + dq * 4 + 0) * 64 + e]);
            o.y = f2bf(W[(h * 64 + dq * 4 + 1) * 64 + e]);
            o.z = f2bf(W[(h * 64 + dq * 4 + 2) * 64 + e]);
            o.w = f2bf(W[(h * 64 + dq * 4 + 3) * 64 + e]);
            *(ushort4*)&wt[(size_t)((pj * 12 + h) * 64 + e) * 64 + dq * 4] = o;
        }
    }
}

// ---------------- gather patches -> bf16 A [12544][768] ----------------
__global__ void k_prep_patches(const float* __restrict__ img, ushort_t* __restrict__ Ae) {
    int idx = blockIdx.x * 256 + threadIdx.x;       // 0 .. 12544*192
    int m = idx / 192, kq = idx % 192;
    int k0 = kq * 4;
    int c = k0 >> 8, rem = k0 & 255, ir = rem >> 4, jc = rem & 15;
    int b = m / 196, pi = m % 196;
    int pr = pi / 14, pc = pi % 14;
    float4 v = *(const float4*)&img[((b * 3 + c) * 224 + pr * 16 + ir) * 224 + pc * 16 + jc];
    ushort4 o;
    o.x = f2bf(v.x); o.y = f2bf(v.y); o.z = f2bf(v.z); o.w = f2bf(v.w);
    *(ushort4*)&Ae[m * 768 + k0] = o;
}

// ---------------- bf16 MFMA GEMM, 128x128 tile, BK=64, 4 waves ----------------
// MODE 0 (embed): writes tok and accumulates LN1 raw sums into stats[0..128)
// MODE 1 (enc):   out += relu(A@B + bias)
template <int MODE>
__launch_bounds__(256)
__global__ void k_gemm_bf16(const ushort_t* __restrict__ A, const ushort_t* __restrict__ Bt,
                            const float* __restrict__ bias, const float* __restrict__ pos,
                            float* __restrict__ out, int Mtot, float* __restrict__ stats) {
    __shared__ ushort_t As[128 * 64];
    __shared__ ushort_t Bs[128 * 64];
    __shared__ float redS[4][4];
    const int m0 = blockIdx.x * 128;
    const int n0 = blockIdx.y * 128;
    const int tid = threadIdx.x;
    const int lane = tid & 63, wave = tid >> 6;
    const int wm = wave >> 1, wn = wave & 1;

    f32x4 acc[4][4];
#pragma unroll
    for (int i = 0; i < 4; ++i)
#pragma unroll
        for (int j = 0; j < 4; ++j)
#pragma unroll
            for (int r = 0; r < 4; ++r) acc[i][j][r] = 0.f;

    for (int kt = 0; kt < 12; ++kt) {
        const int k0 = kt * 64;
#pragma unroll
        for (int t = 0; t < 4; ++t) {
            int c = (wave << 2) | t;
            int o = c * 1024 + lane * 16;
            int row = o >> 7;
            int inner = o & 127;
            int col = (inner ^ ((row & 7) << 4)) >> 1;
            gload16(&A[(size_t)(m0 + row) * 768 + k0 + col], &As[c * 512]);
            gload16(&Bt[(size_t)(n0 + row) * 768 + k0 + col], &Bs[c * 512]);
        }
        __syncthreads();
#pragma unroll
        for (int ks = 0; ks < 2; ++ks) {
            const int cbyte = ks * 64 + (lane >> 4) * 16;
            bf16x8 af[4], bf[4];
#pragma unroll
            for (int mi = 0; mi < 4; ++mi) {
                int row = wm * 64 + mi * 16 + (lane & 15);
                af[mi] = *(const bf16x8*)((const char*)As + row * 128 + (cbyte ^ ((row & 7) << 4)));
            }
#pragma unroll
            for (int ni = 0; ni < 4; ++ni) {
                int n = wn * 64 + ni * 16 + (lane & 15);
                bf[ni] = *(const bf16x8*)((const char*)Bs + n * 128 + (cbyte ^ ((n & 7) << 4)));
            }
#pragma unroll
            for (int mi = 0; mi < 4; ++mi)
#pragma unroll
                for (int ni = 0; ni < 4; ++ni)
                    acc[mi][ni] = __builtin_amdgcn_mfma_f32_16x16x32_bf16(af[mi], bf[ni], acc[mi][ni], 0, 0, 0);
        }
        __syncthreads();
    }

    const int colb = n0 + wn * 64 + (lane & 15);
    const int rowb = m0 + wm * 64 + (lane >> 4) * 4;
    float s_lo = 0.f, q_lo = 0.f, s_hi = 0.f, q_hi = 0.f;
    const int bA = m0 / 196;
    const int mSplit = (bA + 1) * 196;
#pragma unroll
    for (int ni = 0; ni < 4; ++ni) {
        const int n = colb + ni * 16;
        const float bn = bias[n];
#pragma unroll
        for (int mi = 0; mi < 4; ++mi) {
#pragma unroll
            for (int r = 0; r < 4; ++r) {
                int m = rowb + mi * 16 + r;
                if (MODE == 0) {
                    int b = m / 196, s = 1 + m % 196;
                    float oval = acc[mi][ni][r] + bn + pos[s * HD + n];
                    out[((b * SEQL) + s) * HD + n] = oval;
                    if (m < mSplit) { s_lo += oval; q_lo += oval * oval; }
                    else            { s_hi += oval; q_hi += oval * oval; }
                } else {
                    if (m < Mtot) {
                        float* p = &out[(size_t)m * HD + n];
                        *p = *p + fmaxf(acc[mi][ni][r] + bn, 0.f);
                    }
                }
            }
        }
    }
    if (MODE == 0) {
#pragma unroll
        for (int off = 32; off > 0; off >>= 1) {
            s_lo += __shfl_down(s_lo, off);
            q_lo += __shfl_down(q_lo, off);
            s_hi += __shfl_down(s_hi, off);
            q_hi += __shfl_down(q_hi, off);
        }
        if (lane == 0) {
            redS[wave][0] = s_lo; redS[wave][1] = q_lo;
            redS[wave][2] = s_hi; redS[wave][3] = q_hi;
        }
        __syncthreads();
        if (tid == 0) {
            float a0 = 0.f, a1 = 0.f, a2 = 0.f, a3 = 0.f;
#pragma unroll
            for (int i = 0; i < 4; ++i) {
                a0 += redS[i][0]; a1 += redS[i][1];
                a2 += redS[i][2]; a3 += redS[i][3];
            }
            atomicAdd(&stats[2 * bA], a0);
            atomicAdd(&stats[2 * bA + 1], a1);
            int bB = bA + 1;
            if (bB < BATCH) {
                atomicAdd(&stats[2 * bB], a2);
                atomicAdd(&stats[2 * bB + 1], a3);
            }
        }
    }
}

// ---------------- FUSED: LN1 + QKV projections + attention + residual ----------
// Round-8 structure (1 block/(h,b), 8 waves). LN1 mu/rsg finalized inline from
// raw sums; no-max softmax (|scores| <~ 1.5); coalesced epilogue via O-staging
// in the dead K/V LDS region; LN2 raw sums accumulated at the end.
__launch_bounds__(512, 2)
__global__ void k_qkvattn(const float* __restrict__ tok, float* __restrict__ stats,
                          const float* __restrict__ g1, const float* __restrict__ b1,
                          const ushort_t* __restrict__ wt,
                          const float* __restrict__ bq, const float* __restrict__ bk,
                          const float* __restrict__ bv, float* __restrict__ out) {
    const int h = blockIdx.x, b = blockIdx.y;
    __shared__ __attribute__((aligned(16))) ushort_t sm[51712];
    __shared__ float rS[8], rS2[8];
    const int tid = threadIdx.x;
    const int wave = tid >> 6, lane = tid & 63;
    const int l16 = lane & 15, l4 = lane >> 4;
    const int r0 = wave * 32;
    const float inv_n = 1.0f / (float)(SEQL * HD);
    const float S1_ = stats[b * 2], S2_ = stats[b * 2 + 1];
    const float mu = S1_ * inv_n;
    const float rsg = rsqrtf(S2_ * inv_n - mu * mu + 1e-5f);

    // ---- stage LN1(X) rows (each wave stages exactly its own 32 rows) ----
    {
        const int row = tid >> 1, hw = tid & 1;
        if (row < SEQL) {
            const float* tp = &tok[((size_t)b * SEQL + row) * HD + h * 64 + hw * 32];
            const float* gp = &g1[(size_t)row * HD + h * 64 + hw * 32];
            const float* bp = &b1[(size_t)row * HD + h * 64 + hw * 32];
#pragma unroll
            for (int g = 0; g < 4; ++g) {
                float4 t0 = *(const float4*)&tp[g * 8];
                float4 t1 = *(const float4*)&tp[g * 8 + 4];
                float4 ga = *(const float4*)&gp[g * 8];
                float4 gb = *(const float4*)&gp[g * 8 + 4];
                float4 ba = *(const float4*)&bp[g * 8];
                float4 bb = *(const float4*)&bp[g * 8 + 4];
                bf16x8 o;
                o[0] = (short)f2bf((t0.x - mu) * rsg * ga.x + ba.x);
                o[1] = (short)f2bf((t0.y - mu) * rsg * ga.y + ba.y);
                o[2] = (short)f2bf((t0.z - mu) * rsg * ga.z + ba.z);
                o[3] = (short)f2bf((t0.w - mu) * rsg * ga.w + ba.w);
                o[4] = (short)f2bf((t1.x - mu) * rsg * gb.x + bb.x);
                o[5] = (short)f2bf((t1.y - mu) * rsg * gb.y + bb.y);
                o[6] = (short)f2bf((t1.z - mu) * rsg * gb.z + bb.z);
                o[7] = (short)f2bf((t1.w - mu) * rsg * gb.w + bb.w);
                int pc = (hw * 32 + g * 8) ^ ((row & 7) << 3);
                *(bf16x8*)&sm[row * 64 + pc] = o;
            }
        } else {
            bf16x8 z;
#pragma unroll
            for (int j = 0; j < 8; ++j) z[j] = 0;
#pragma unroll
            for (int g = 0; g < 4; ++g) {
                int pc = (hw * 32 + g * 8) ^ ((row & 7) << 3);
                *(bf16x8*)&sm[row * 64 + pc] = z;
            }
        }
    }

    // A fragments from own rows (wave-private slice; no barrier needed)
    bf16x8 af[2][2];
#pragma unroll
    for (int mi = 0; mi < 2; ++mi)
#pragma unroll
        for (int kk = 0; kk < 2; ++kk) {
            int row = r0 + mi * 16 + l16;
            af[mi][kk] = *(const bf16x8*)&sm[row * 64 + ((kk * 32 + l4 * 8) ^ ((row & 7) << 3))];
        }

    ushort_t* myS = &sm[wave * 2048];   // wave-private 32x64 slice (Qtmp, then P)

#define PROJ_ACC(PJ, ACC)                                                                      \
    {                                                                                          \
        _Pragma("unroll") for (int ni = 0; ni < 4; ++ni) {                                     \
            const ushort_t* wr = &wt[(size_t)(((PJ) * 12 + h) * 64 + ni * 16 + l16) * 64];     \
            bf16x8 w0 = *(const bf16x8*)&wr[l4 * 8];                                           \
            bf16x8 w1 = *(const bf16x8*)&wr[32 + l4 * 8];                                      \
            _Pragma("unroll") for (int mi = 0; mi < 2; ++mi) {                                 \
                ACC[mi][ni] = __builtin_amdgcn_mfma_f32_16x16x32_bf16(af[mi][0], w0, ACC[mi][ni], 0, 0, 0); \
                ACC[mi][ni] = __builtin_amdgcn_mfma_f32_16x16x32_bf16(af[mi][1], w1, ACC[mi][ni], 0, 0, 0); \
            }                                                                                  \
        }                                                                                      \
    }

    f32x4 acc[2][4];
#define ZERO_ACC                                                                               \
    _Pragma("unroll") for (int mi = 0; mi < 2; ++mi)                                           \
        _Pragma("unroll") for (int ni = 0; ni < 4; ++ni) {                                     \
            acc[mi][ni][0] = 0.f; acc[mi][ni][1] = 0.f; acc[mi][ni][2] = 0.f; acc[mi][ni][3] = 0.f; }

    // ---- Q ----
    ZERO_ACC;
    PROJ_ACC(0, acc);
#pragma unroll
    for (int ni = 0; ni < 4; ++ni) {
        float bn = bq[h * 64 + ni * 16 + l16];
#pragma unroll
        for (int mi = 0; mi < 2; ++mi)
#pragma unroll
            for (int r = 0; r < 4; ++r) {
                int rl = mi * 16 + l4 * 4 + r;
                myS[rl * 64 + ((ni * 16 + l16) ^ ((rl & 7) << 3))] = f2bf(acc[mi][ni][r] + bn);
            }
    }
    bf16x8 qa[2][2];
#pragma unroll
    for (int mi = 0; mi < 2; ++mi)
#pragma unroll
        for (int kk = 0; kk < 2; ++kk) {
            int rl = mi * 16 + l16;
            qa[mi][kk] = *(const bf16x8*)&myS[rl * 64 + ((kk * 32 + l4 * 8) ^ ((rl & 7) << 3))];
        }

    // ---- K ----
    ZERO_ACC;
    PROJ_ACC(1, acc);
#pragma unroll
    for (int ni = 0; ni < 4; ++ni) {
        float bn = bk[h * 64 + ni * 16 + l16];
#pragma unroll
        for (int mi = 0; mi < 2; ++mi)
#pragma unroll
            for (int r = 0; r < 4; ++r) {
                int t = r0 + mi * 16 + l4 * 4 + r;
                sm[16384 + t * 72 + ni * 16 + l16] = f2bf(acc[mi][ni][r] + bn);
            }
    }

    // ---- V (transposed store) ----
    ZERO_ACC;
    PROJ_ACC(2, acc);
#pragma unroll
    for (int ni = 0; ni < 4; ++ni) {
        float bn = bv[h * 64 + ni * 16 + l16];
#pragma unroll
        for (int mi = 0; mi < 2; ++mi)
#pragma unroll
            for (int r = 0; r < 4; ++r) {
                int t = r0 + mi * 16 + l4 * 4 + r;
                sm[34816 + (ni * 16 + l16) * 264 + t] = f2bf(acc[mi][ni][r] + bn);
            }
    }

    __syncthreads();   // K and V^T now visible to all waves

    // ---- QK^T over all 256 t ----
    f32x4 sa[2][16];
#pragma unroll
    for (int ni = 0; ni < 16; ++ni) {
        int t = ni * 16 + l16;
        bf16x8 k0 = *(const bf16x8*)&sm[16384 + t * 72 + l4 * 8];
        bf16x8 k1 = *(const bf16x8*)&sm[16384 + t * 72 + 32 + l4 * 8];
#pragma unroll
        for (int mi = 0; mi < 2; ++mi) {
            f32x4 z;
            z[0] = 0.f; z[1] = 0.f; z[2] = 0.f; z[3] = 0.f;
            z = __builtin_amdgcn_mfma_f32_16x16x32_bf16(qa[mi][0], k0, z, 0, 0, 0);
            sa[mi][ni] = __builtin_amdgcn_mfma_f32_16x16x32_bf16(qa[mi][1], k1, z, 0, 0, 0);
        }
    }

    // ---- softmax per q-row, NO max subtraction (|s| <~ 1.5 by construction) ----
    float l_s[2][4];
#pragma unroll
    for (int mi = 0; mi < 2; ++mi)
#pragma unroll
        for (int r = 0; r < 4; ++r) {
            float rsum = 0.f;
#pragma unroll
            for (int ni = 0; ni < 16; ++ni) {
                float p = (ni * 16 + l16 < SEQL) ? __expf(sa[mi][ni][r] * 0.125f) : 0.f;
                sa[mi][ni][r] = p;
                rsum += p;
            }
            rsum += __shfl_xor(rsum, 1);
            rsum += __shfl_xor(rsum, 2);
            rsum += __shfl_xor(rsum, 4);
            rsum += __shfl_xor(rsum, 8);
            l_s[mi][r] = rsum;
        }

    // ---- PV in 4 chunks of 64 t (P bounced through wave-private slice) ----
    f32x4 oacc[2][4];
#pragma unroll
    for (int mi = 0; mi < 2; ++mi)
#pragma unroll
        for (int ne = 0; ne < 4; ++ne) {
            oacc[mi][ne][0] = 0.f; oacc[mi][ne][1] = 0.f;
            oacc[mi][ne][2] = 0.f; oacc[mi][ne][3] = 0.f;
        }

    for (int c = 0; c < 4; ++c) {
#pragma unroll
        for (int j = 0; j < 4; ++j)
#pragma unroll
            for (int mi = 0; mi < 2; ++mi)
#pragma unroll
                for (int r = 0; r < 4; ++r) {
                    int rl = mi * 16 + l4 * 4 + r;
                    myS[rl * 64 + ((j * 16 + l16) ^ ((rl & 7) << 3))] = f2bf(sa[mi][c * 4 + j][r]);
                }
        bf16x8 pa[2][2];
#pragma unroll
        for (int mi = 0; mi < 2; ++mi)
#pragma unroll
            for (int kk = 0; kk < 2; ++kk) {
                int rl = mi * 16 + l16;
                pa[mi][kk] = *(const bf16x8*)&myS[rl * 64 + ((kk * 32 + l4 * 8) ^ ((rl & 7) << 3))];
            }
#pragma unroll
        for (int ne = 0; ne < 4; ++ne) {
            int e = ne * 16 + l16;
            bf16x8 v0 = *(const bf16x8*)&sm[34816 + e * 264 + c * 64 + l4 * 8];
            bf16x8 v1 = *(const bf16x8*)&sm[34816 + e * 264 + c * 64 + 32 + l4 * 8];
#pragma unroll
            for (int mi = 0; mi < 2; ++mi) {
                oacc[mi][ne] = __builtin_amdgcn_mfma_f32_16x16x32_bf16(pa[mi][0], v0, oacc[mi][ne], 0, 0, 0);
                oacc[mi][ne] = __builtin_amdgcn_mfma_f32_16x16x32_bf16(pa[mi][1], v1, oacc[mi][ne], 0, 0, 0);
            }
        }
    }

    // ---- epilogue v2: O through dead K/V LDS -> coalesced residual + store ----
    __syncthreads();   // all waves done with K/V regions
    float* Osm = (float*)&sm[16384] + wave * 2176;   // per-wave [32][68] f32
#pragma unroll
    for (int mi = 0; mi < 2; ++mi)
#pragma unroll
        for (int r = 0; r < 4; ++r) {
            float inv = 1.0f / l_s[mi][r];
            int rl = mi * 16 + l4 * 4 + r;
#pragma unroll
            for (int ne = 0; ne < 4; ++ne)
                Osm[rl * 68 + ne * 16 + l16] = oacc[mi][ne][r] * inv;
        }
    float psum = 0.f, psq = 0.f;
#pragma unroll
    for (int it = 0; it < 8; ++it) {
        int rl = it * 4 + l4;
        int row = r0 + rl;
        if (row < SEQL) {
            size_t off = ((size_t)b * SEQL + row) * HD + h * 64 + l16 * 4;
            float4 ov = *(float4*)&Osm[rl * 68 + l16 * 4];
            float4 tv = *(const float4*)&tok[off];
            float4 o;
            o.x = ov.x + tv.x; o.y = ov.y + tv.y;
            o.z = ov.z + tv.z; o.w = ov.w + tv.w;
            *(float4*)&out[off] = o;
            psum += o.x + o.y + o.z + o.w;
            psq  += o.x * o.x + o.y * o.y + o.z * o.z + o.w * o.w;
        }
    }
#pragma unroll
    for (int off = 32; off > 0; off >>= 1) {
        psum += __shfl_down(psum, off);
        psq += __shfl_down(psq, off);
    }
    if (lane == 0) { rS[wave] = psum; rS2[wave] = psq; }
    __syncthreads();
    if (tid == 0) {
        float S = 0.f, S2 = 0.f;
#pragma unroll
        for (int i = 0; i < 8; ++i) { S += rS[i]; S2 += rS2[i]; }
        atomicAdd(&stats[128 + 2 * b], S);
        atomicAdd(&stats[129 + 2 * b], S2);
    }
#undef PROJ_ACC
#undef ZERO_ACC
}

// ---------------- LN2 apply (finalizes stats from raw sums) -> bf16 ----------------
__global__ void k_ln2apply(const float* __restrict__ outb, const float* __restrict__ stats,
                           const float* __restrict__ g2, const float* __restrict__ b2,
                           ushort_t* __restrict__ x) {
    int i = blockIdx.x * 256 + threadIdx.x;
    if (i >= BATCH * SEQL * HD / 4) return;
    int e4 = i * 4;
    int m = e4 / HD, kk = e4 % HD;
    int b = m / SEQL, s = m % SEQL;
    const float inv_n = 1.0f / (float)(SEQL * HD);
    float S = stats[128 + 2 * b], S2 = stats[129 + 2 * b];
    float mu = S * inv_n;
    float rsg = rsqrtf(S2 * inv_n - mu * mu + 1e-5f);
    float4 t = *(const float4*)&outb[e4];
    float4 g = *(const float4*)&g2[s * HD + kk];
    float4 bb = *(const float4*)&b2[s * HD + kk];
    ushort4 o;
    o.x = f2bf((t.x - mu) * rsg * g.x + bb.x);
    o.y = f2bf((t.y - mu) * rsg * g.y + bb.y);
    o.z = f2bf((t.z - mu) * rsg * g.z + bb.z);
    o.w = f2bf((t.w - mu) * rsg * g.w + bb.w);
    *(ushort4*)&x[e4] = o;
}

// ---------------- classifier head + softmax ----------------
__launch_bounds__(256)
__global__ void k_head(const float* __restrict__ out, const float* __restrict__ Wo,
                       const float* __restrict__ bo, float* __restrict__ dout) {
    const int b = blockIdx.x, tid = threadIdx.x;
    __shared__ float cls[768];
    __shared__ float red[256];
    for (int i = tid; i < 192; i += 256)
        *(float4*)&cls[i * 4] = *(const float4*)&out[(b * SEQL) * HD + i * 4];
    __syncthreads();

    const int o0 = tid * 4;
    const bool ok = (o0 < OUTD);
    float4 acc = {0.f, 0.f, 0.f, 0.f};
    if (ok) {
        acc = *(const float4*)&bo[o0];
        for (int e = 0; e < 768; ++e) {
            float c = cls[e];
            float4 w = *(const float4*)&Wo[e * OUTD + o0];
            acc.x += c * w.x;
            acc.y += c * w.y;
            acc.z += c * w.z;
            acc.w += c * w.w;
        }
    }
    float mx = ok ? fmaxf(fmaxf(acc.x, acc.y), fmaxf(acc.z, acc.w)) : -INFINITY;
    red[tid] = mx;
    __syncthreads();
    for (int s = 128; s > 0; s >>= 1) {
        if (tid < s) red[tid] = fmaxf(red[tid], red[tid + s]);
        __syncthreads();
    }
    float M = red[0];
    __syncthreads();
    float4 p = {0.f, 0.f, 0.f, 0.f};
    float ls = 0.f;
    if (ok) {
        p.x = expf(acc.x - M);
        p.y = expf(acc.y - M);
        p.z = expf(acc.z - M);
        p.w = expf(acc.w - M);
        ls = p.x + p.y + p.z + p.w;
    }
    red[tid] = ls;
    __syncthreads();
    for (int s = 128; s > 0; s >>= 1) {
        if (tid < s) red[tid] += red[tid + s];
        __syncthreads();
    }
    float inv = 1.0f / red[0];
    if (ok) {
        p.x *= inv; p.y *= inv; p.z *= inv; p.w *= inv;
        *(float4*)&dout[b * OUTD + o0] = p;
    }
}

extern "C" void kernel_launch(void* const* d_in, const int* in_sizes, int n_in,
                              void* d_out, int out_size, void* d_ws, size_t ws_size,
                              hipStream_t stream) {
    const float* images  = (const float*)d_in[0];
    const float* W_map   = (const float*)d_in[1];
    const float* b_map   = (const float*)d_in[2];
    const float* cls_tok = (const float*)d_in[3];
    const float* ln1_g   = (const float*)d_in[4];
    const float* ln1_b   = (const float*)d_in[5];
    const float* Wq      = (const float*)d_in[6];
    const float* bq      = (const float*)d_in[7];
    const float* Wk      = (const float*)d_in[8];
    const float* bk      = (const float*)d_in[9];
    const float* Wv      = (const float*)d_in[10];
    const float* bv      = (const float*)d_in[11];
    const float* ln2_g   = (const float*)d_in[12];
    const float* ln2_b   = (const float*)d_in[13];
    const float* W_enc   = (const float*)d_in[14];
    const float* b_enc   = (const float*)d_in[15];
    const float* W_out   = (const float*)d_in[16];
    const float* b_out   = (const float*)d_in[17];

    float* ws = (float*)d_ws;
    const size_t BIG = (size_t)BATCH * SEQL * HD;     // 9,682,944

    float* pos   = ws;
    float* tok   = ws + 151552;
    float* outb  = tok + BIG;
    float* stats = outb + BIG;                        // 256 f32: [0,128) LN1 raw, [128,256) LN2 raw
    ushort_t* wtq = (ushort_t*)(stats + 256);         // bf16 [3][12][64][64] = 147,456
    ushort_t* Ae  = wtq + 147456;                     // bf16 [12672][768] (patches, then LN2 out)
    ushort_t* WmT = Ae + (size_t)12672 * 768;         // bf16 [768][768]
    ushort_t* WeT = WmT + (size_t)768 * 768;          // bf16 [768][768]
    ushort_t* Ae2 = Ae;                               // LN2-out bf16 (Ae dead after embed GEMM)

    k_cvtAll<<<1296, 256, 0, stream>>>(W_map, W_enc, Wq, Wk, Wv, WmT, WeT, wtq, stats);
    k_init<<<783, 256, 0, stream>>>(cls_tok, pos, tok, stats);
    k_prep_patches<<<9408, 256, 0, stream>>>(images, Ae);
    k_gemm_bf16<0><<<dim3(98, 6), 256, 0, stream>>>(Ae, WmT, b_map, pos, tok, 12544, stats);
    k_qkvattn<<<dim3(12, 64), 512, 0, stream>>>(tok, stats, ln1_g, ln1_b, wtq, bq, bk, bv, outb);
    k_ln2apply<<<9456, 256, 0, stream>>>(outb, stats, ln2_g, ln2_b, Ae2);
    k_gemm_bf16<1><<<dim3(99, 6), 256, 0, stream>>>(Ae2, WeT, b_enc, pos, outb, 12608, stats);
    k_head<<<64, 256, 0, stream>>>(outb, W_out, b_out, (float*)d_out);
}